// Round 5
// baseline (326.674 us; speedup 1.0000x reference)
//
#include <hip/hip_runtime.h>
#include <math.h>

typedef __bf16 bf16_t;
typedef bf16_t bf16x8 __attribute__((ext_vector_type(8)));
typedef float  f32x4  __attribute__((ext_vector_type(4)));
typedef unsigned short u16;

#define B_SZ   16384
#define H_SZ   50
#define NI_SZ  100000
#define SCALE  0.08838834764831845f   /* 1/sqrt(128) */
#define FRAG_W 32768                  /* u16 elems per W (hi 16384 + lo 16384) */

// Logical-k bijection used consistently for A and B frags of
// mfma_f32_16x16x32_bf16:  k = kk*32 + 16*(e>>2) + 4*l4 + (e&3).
// C/D layout (HW): col = lane&15, row = (lane>>4)*4 + reg.

// ---------------------------------------------------------------------------
// Prep: W[k][n] (f32 128x128) -> frag-ready hi/lo bf16; a wave's (kk,nblk)
// B-frag read is 1024 contiguous bytes at ((kk*8+nblk)*64+lane)*8.
// ---------------------------------------------------------------------------
struct WPtrs { const float* p[8]; };

__global__ void prep_frags(WPtrs wp, u16* __restrict__ dst)
{
    int tid = blockIdx.x * 256 + threadIdx.x;      // 8 * 16384 threads
    int w = tid >> 14, idx = tid & 16383;
    int k = idx >> 7, n = idx & 127;
    float v = wp.p[w][idx];
    bf16_t hi = (bf16_t)v;
    bf16_t lo = (bf16_t)(v - (float)hi);
    int kk = k >> 5, k32 = k & 31;
    int e  = ((k32 >> 4) & 1) * 4 + (k32 & 3);
    int l4 = (k32 >> 2) & 3;
    int lane = l4 * 16 + (n & 15);
    int pos = ((kk * 8 + (n >> 4)) * 64 + lane) * 8 + e;
    union { bf16_t b; u16 u; } ch, cl; ch.b = hi; cl.b = lo;
    dst[(size_t)w * FRAG_W + pos]         = ch.u;
    dst[(size_t)w * FRAG_W + 16384 + pos] = cl.u;
}

// ---------------------------------------------------------------------------
// Shared device helpers
// ---------------------------------------------------------------------------
__device__ __forceinline__ void repack8(f32x4 a0, f32x4 a1, bf16x8& hi, bf16x8& lo)
{
#pragma unroll
    for (int e = 0; e < 4; ++e) {
        bf16_t h0 = (bf16_t)a0[e]; hi[e] = h0; lo[e] = (bf16_t)(a0[e] - (float)h0);
        bf16_t h1 = (bf16_t)a1[e]; hi[4 + e] = h1; lo[4 + e] = (bf16_t)(a1[e] - (float)h1);
    }
}

// 16x128 @ 128x128, 3-term split-bf16 (~fp32), acc C-layout
__device__ __forceinline__ void gemm3(const bf16x8 ahi[4], const bf16x8 alo[4],
                                      const u16* __restrict__ fh, int lane, f32x4 acc[8])
{
#pragma unroll
    for (int kk = 0; kk < 4; ++kk)
#pragma unroll
        for (int n = 0; n < 8; ++n) {
            int foff = ((kk * 8 + n) * 64 + lane) * 8;
            bf16x8 bhi = *(const bf16x8*)(fh + foff);
            bf16x8 blo = *(const bf16x8*)(fh + 16384 + foff);
            acc[n] = __builtin_amdgcn_mfma_f32_16x16x32_bf16(ahi[kk], bhi, acc[n], 0, 0, 0);
            acc[n] = __builtin_amdgcn_mfma_f32_16x16x32_bf16(alo[kk], bhi, acc[n], 0, 0, 0);
            acc[n] = __builtin_amdgcn_mfma_f32_16x16x32_bf16(ahi[kk], blo, acc[n], 0, 0, 0);
        }
}

__device__ __forceinline__ void zero8(f32x4 acc[8])
{
#pragma unroll
    for (int n = 0; n < 8; ++n) acc[n] = (f32x4){0.f, 0.f, 0.f, 0.f};
}

// Load a contiguous/gathered 16x128 f32 tile as A-frags (lane l15 = row)
__device__ __forceinline__ void load_afrags(const float* __restrict__ Ar, int l4,
                                            bf16x8 ahi[4], bf16x8 alo[4])
{
#pragma unroll
    for (int kk = 0; kk < 4; ++kk) {
        f32x4 a0 = *(const f32x4*)(Ar + kk * 32 + 4 * l4);
        f32x4 a1 = *(const f32x4*)(Ar + kk * 32 + 16 + 4 * l4);
        repack8(a0, a1, ahi[kk], alo[kk]);
    }
}

// C-layout acc -> global f32 with bias + relu
__device__ __forceinline__ void store_c(float* __restrict__ dst, const f32x4 acc[8],
                                        const float* __restrict__ bias,
                                        int row0, int l15, int l4)
{
#pragma unroll
    for (int n = 0; n < 8; ++n) {
        float bv = bias[n * 16 + l15];
#pragma unroll
        for (int r = 0; r < 4; ++r) {
            float v = acc[n][r] + bv;
            v = v > 0.f ? v : 0.f;
            dst[(size_t)(row0 + l4 * 4 + r) * 128 + n * 16 + l15] = v;
        }
    }
}

// Wave-private LDS transpose: C-layout f32 tile -> A-frags (hi/lo bf16).
// Sw is 16*132 floats, wave-private.
__device__ __forceinline__ void lds_c_write(float* __restrict__ Sw, const float vals[8][4],
                                            int l15, int l4)
{
#pragma unroll
    for (int n = 0; n < 8; ++n)
#pragma unroll
        for (int r = 0; r < 4; ++r)
            Sw[(l4 * 4 + r) * 132 + n * 16 + l15] = vals[n][r];
}

__device__ __forceinline__ void lds_read_afrags(const float* __restrict__ Sw, int l15, int l4,
                                                bf16x8 ahi[4], bf16x8 alo[4])
{
#pragma unroll
    for (int kk = 0; kk < 4; ++kk) {
        f32x4 a0 = *(const f32x4*)(Sw + l15 * 132 + kk * 32 + 4 * l4);
        f32x4 a1 = *(const f32x4*)(Sw + l15 * 132 + kk * 32 + 16 + 4 * l4);
        repack8(a0, a1, ahi[kk], alo[kk]);
    }
}

#define LGKM_FENCE() do { \
    __asm__ volatile("s_waitcnt lgkmcnt(0)" ::: "memory"); \
    __builtin_amdgcn_sched_barrier(0); } while (0)

// ---------------------------------------------------------------------------
// Item K+V GEMM (bf16 single-term, bf16 out via LDS bounce -> 1KB wave stores)
// One wave = one (16-row tile, weight) unit.
// ---------------------------------------------------------------------------
__global__ __launch_bounds__(256, 4)
void item_kv(const float* __restrict__ A, const u16* __restrict__ frags,
             const float* __restrict__ bk, const float* __restrict__ bv,
             u16* __restrict__ kt, u16* __restrict__ vt)
{
    __shared__ u16 bounce[4 * 16 * 136];
    const int t = threadIdx.x, wave = t >> 6, lane = t & 63;
    const int l15 = lane & 15, l4 = lane >> 4;
    const int totalUnits = (NI_SZ >> 4) * 2;           // 12500

    for (int unit = blockIdx.x * 4 + wave; unit < totalUnits; unit += gridDim.x * 4) {
        const int w = unit & 1, tile = unit >> 1;
        const int row0 = tile * 16;
        const float* bias = w ? bv : bk;
        u16* out = w ? vt : kt;
        const u16* fh = frags + (size_t)(w ? 2 : 1) * FRAG_W;

        const float* Ar = A + (size_t)(row0 + l15) * 128;
        bf16x8 ahi[4];
#pragma unroll
        for (int kk = 0; kk < 4; ++kk) {
            f32x4 a0 = *(const f32x4*)(Ar + kk * 32 + 4 * l4);
            f32x4 a1 = *(const f32x4*)(Ar + kk * 32 + 16 + 4 * l4);
#pragma unroll
            for (int e = 0; e < 4; ++e) {
                ahi[kk][e]     = (bf16_t)a0[e];
                ahi[kk][4 + e] = (bf16_t)a1[e];
            }
        }

        f32x4 acc[8];
        zero8(acc);
#pragma unroll
        for (int kk = 0; kk < 4; ++kk)
#pragma unroll
            for (int n = 0; n < 8; ++n) {
                int foff = ((kk * 8 + n) * 64 + lane) * 8;
                bf16x8 bhi = *(const bf16x8*)(fh + foff);
                acc[n] = __builtin_amdgcn_mfma_f32_16x16x32_bf16(ahi[kk], bhi, acc[n], 0, 0, 0);
            }

        u16* bb = bounce + wave * (16 * 136);
#pragma unroll
        for (int n = 0; n < 8; ++n) {
            float bvn = bias[n * 16 + l15];
#pragma unroll
            for (int r = 0; r < 4; ++r) {
                float v = acc[n][r] + bvn;
                v = v > 0.f ? v : 0.f;
                union { bf16_t b; u16 u; } c; c.b = (bf16_t)v;
                bb[(l4 * 4 + r) * 136 + n * 16 + l15] = c.u;
            }
        }
        LGKM_FENCE();
#pragma unroll
        for (int j = 0; j < 4; ++j) {
            int row = j * 4 + l4;
            const u16* sp = bb + row * 136 + l15 * 8;
            u16* ob = out + (size_t)(row0 + row) * 128 + l15 * 8;
            *(ulonglong2*)ob = *(const ulonglong2*)sp;
        }
        LGKM_FENCE();   // bounce reuse safety across grid-stride iterations
    }
}

// ---------------------------------------------------------------------------
// Fused node projections: qg = relu(node@gwq+gbq), qs = relu(node@swq+sbq),
// k1 (regs only) = relu(node@swk+sbk), v1 = relu(node@swv+sbv),
// d1[b] = qs[b] . k1[b].   One wave per 16-row tile (1024 tiles).
// ---------------------------------------------------------------------------
__global__ __launch_bounds__(256, 1)
void node4_fused(const float* __restrict__ ut, const int* __restrict__ uids,
                 const u16* __restrict__ frags,
                 const float* __restrict__ gbq, const float* __restrict__ sbq,
                 const float* __restrict__ sbk, const float* __restrict__ sbv,
                 float* __restrict__ qg, float* __restrict__ qs,
                 float* __restrict__ v1, float* __restrict__ d1g)
{
    const int t = threadIdx.x, wave = t >> 6, lane = t & 63;
    const int l15 = lane & 15, l4 = lane >> 4;
    const int tile = blockIdx.x * 4 + wave;
    const int row0 = tile * 16;

    const float* Ar = ut + (size_t)uids[row0 + l15] * 128;
    bf16x8 ahi[4], alo[4];
    load_afrags(Ar, l4, ahi, alo);

    f32x4 acc[8];

    // qg
    zero8(acc);
    gemm3(ahi, alo, frags + 0 * FRAG_W, lane, acc);
    store_c(qg, acc, gbq, row0, l15, l4);

    // qs (keep in regs for d1)
    float qsr[8][4];
    zero8(acc);
    gemm3(ahi, alo, frags + 4 * FRAG_W, lane, acc);
#pragma unroll
    for (int n = 0; n < 8; ++n) {
        float bv = sbq[n * 16 + l15];
#pragma unroll
        for (int r = 0; r < 4; ++r) {
            float v = acc[n][r] + bv;
            qsr[n][r] = v > 0.f ? v : 0.f;
            qs[(size_t)(row0 + l4 * 4 + r) * 128 + n * 16 + l15] = qsr[n][r];
        }
    }

    // k1 (regs only) + d1
    zero8(acc);
    gemm3(ahi, alo, frags + 5 * FRAG_W, lane, acc);
    float d1[4] = {0.f, 0.f, 0.f, 0.f};
#pragma unroll
    for (int n = 0; n < 8; ++n) {
        float bv = sbk[n * 16 + l15];
#pragma unroll
        for (int r = 0; r < 4; ++r) {
            float v = acc[n][r] + bv;
            v = v > 0.f ? v : 0.f;
            d1[r] += qsr[n][r] * v;
        }
    }
#pragma unroll
    for (int r = 0; r < 4; ++r) {
#pragma unroll
        for (int off = 8; off; off >>= 1) d1[r] += __shfl_xor(d1[r], off);
    }
    if (l15 == 0) {
#pragma unroll
        for (int r = 0; r < 4; ++r) d1g[row0 + l4 * 4 + r] = d1[r];
    }

    // v1
    zero8(acc);
    gemm3(ahi, alo, frags + 6 * FRAG_W, lane, acc);
    store_c(v1, acc, sbv, row0, l15, l4);
}

// ---------------------------------------------------------------------------
// GAT attention: wave per batch row, V preloaded to regs.
// ---------------------------------------------------------------------------
__global__ __launch_bounds__(256)
void gat_attn(const float* __restrict__ qg, const u16* __restrict__ kt,
              const u16* __restrict__ vt, const int* __restrict__ um,
              float* __restrict__ y)
{
    __shared__ float qsh[4][128];
    const int wave = threadIdx.x >> 6, lane = threadIdx.x & 63;
    const int b = blockIdx.x * 4 + wave;

    float2 q2 = *(const float2*)(qg + (size_t)b * 128 + lane * 2);
    qsh[wave][lane * 2]     = q2.x;
    qsh[wave][lane * 2 + 1] = q2.y;

    int mrow = (lane < H_SZ) ? um[((size_t)b * H_SZ + lane) * 2] : 0;

    unsigned vreg[H_SZ];
#pragma unroll
    for (int h = 0; h < H_SZ; ++h) {
        int vr = __shfl(mrow, h);
        vreg[h] = *(const unsigned*)(vt + (size_t)vr * 128 + lane * 2);
    }
    __syncthreads();

    float s = -1e30f;
    if (lane < H_SZ) {
        const u16* kr = kt + (size_t)mrow * 128;
        float acc = 0.f;
#pragma unroll
        for (int c = 0; c < 4; ++c) {
            bf16x8 kc[4];
#pragma unroll
            for (int j = 0; j < 4; ++j) kc[j] = *(const bf16x8*)(kr + (c * 4 + j) * 8);
#pragma unroll
            for (int j = 0; j < 4; ++j)
#pragma unroll
                for (int e = 0; e < 8; ++e)
                    acc += (float)kc[j][e] * qsh[wave][(c * 4 + j) * 8 + e];
        }
        s = acc * SCALE;
    }
    float m = s;
#pragma unroll
    for (int off = 32; off; off >>= 1) m = fmaxf(m, __shfl_xor(m, off));
    float p = (lane < H_SZ) ? __expf(s - m) : 0.f;
    float sum = p;
#pragma unroll
    for (int off = 32; off; off >>= 1) sum += __shfl_xor(sum, off);
    p /= sum;

    float ax = 0.f, ay = 0.f;
#pragma unroll
    for (int h = 0; h < H_SZ; ++h) {
        float ph = __shfl(p, h);
        unsigned u = vreg[h];
        ax += ph * __uint_as_float(u << 16);
        ay += ph * __uint_as_float(u & 0xffff0000u);
    }
    *(float2*)(y + (size_t)b * 128 + lane * 2) = (float2){ax, ay};
}

// ---------------------------------------------------------------------------
// Fused semantic stage: per 16-row tile (one wave):
//   agg = relu(yb@gwo+gbo)            (MFMA, LDS-transposed to A-frags)
//   k2  = relu(agg@swk+sbk)  (regs)
//   v2  = relu(agg@swv+sbv)  (regs)
//   d2  = qs . k2 ; softmax(d1,d2) ; ys = p1*v1 + p2*v2
//   out = relu(ys@swo+sbo)
// ---------------------------------------------------------------------------
__global__ __launch_bounds__(256, 1)
void sem_fused(const float* __restrict__ yb, const float* __restrict__ qs,
               const float* __restrict__ v1, const float* __restrict__ d1g,
               const u16* __restrict__ frags,
               const float* __restrict__ gbo, const float* __restrict__ sbk,
               const float* __restrict__ sbv, const float* __restrict__ sbo,
               float* __restrict__ outf)
{
    __shared__ float S[4][16 * 132];
    const int t = threadIdx.x, wave = t >> 6, lane = t & 63;
    const int l15 = lane & 15, l4 = lane >> 4;
    float* Sw = S[wave];
    const int tile = blockIdx.x * 4 + wave;
    const int row0 = tile * 16;

    // ---- stage 1: agg
    bf16x8 ahi[4], alo[4];
    load_afrags(yb + (size_t)(row0 + l15) * 128, l4, ahi, alo);
    f32x4 acc[8];
    zero8(acc);
    gemm3(ahi, alo, frags + 3 * FRAG_W, lane, acc);

    float stg[8][4];
#pragma unroll
    for (int n = 0; n < 8; ++n) {
        float bv = gbo[n * 16 + l15];
#pragma unroll
        for (int r = 0; r < 4; ++r) {
            float v = acc[n][r] + bv;
            stg[n][r] = v > 0.f ? v : 0.f;
        }
    }
    lds_c_write(Sw, stg, l15, l4);
    LGKM_FENCE();
    lds_read_afrags(Sw, l15, l4, ahi, alo);     // agg as A-frags

    // ---- stage 2: k2, v2
    float k2r[8][4], v2r[8][4];
    zero8(acc);
    gemm3(ahi, alo, frags + 5 * FRAG_W, lane, acc);
#pragma unroll
    for (int n = 0; n < 8; ++n) {
        float bv = sbk[n * 16 + l15];
#pragma unroll
        for (int r = 0; r < 4; ++r) {
            float v = acc[n][r] + bv;
            k2r[n][r] = v > 0.f ? v : 0.f;
        }
    }
    zero8(acc);
    gemm3(ahi, alo, frags + 6 * FRAG_W, lane, acc);
#pragma unroll
    for (int n = 0; n < 8; ++n) {
        float bv = sbv[n * 16 + l15];
#pragma unroll
        for (int r = 0; r < 4; ++r) {
            float v = acc[n][r] + bv;
            v2r[n][r] = v > 0.f ? v : 0.f;
        }
    }

    // ---- semantic attention (2 keys) per row
    float d2[4] = {0.f, 0.f, 0.f, 0.f};
#pragma unroll
    for (int n = 0; n < 8; ++n) {
#pragma unroll
        for (int r = 0; r < 4; ++r) {
            float q = qs[(size_t)(row0 + l4 * 4 + r) * 128 + n * 16 + l15];
            d2[r] += q * k2r[n][r];
        }
    }
#pragma unroll
    for (int r = 0; r < 4; ++r) {
#pragma unroll
        for (int off = 8; off; off >>= 1) d2[r] += __shfl_xor(d2[r], off);
    }
    float p1[4], p2[4];
#pragma unroll
    for (int r = 0; r < 4; ++r) {
        float s1 = d1g[row0 + l4 * 4 + r] * SCALE;
        float s2 = d2[r] * SCALE;
        float m = fmaxf(s1, s2);
        float e1 = __expf(s1 - m), e2 = __expf(s2 - m);
        float inv = 1.f / (e1 + e2);
        p1[r] = e1 * inv; p2[r] = e2 * inv;
    }
    // ys = p1*v1 + p2*v2   (reuse stg)
#pragma unroll
    for (int n = 0; n < 8; ++n) {
#pragma unroll
        for (int r = 0; r < 4; ++r) {
            float vv1 = v1[(size_t)(row0 + l4 * 4 + r) * 128 + n * 16 + l15];
            stg[n][r] = p1[r] * vv1 + p2[r] * v2r[n][r];
        }
    }

    // ---- stage 3: out = relu(ys@swo+sbo)
    LGKM_FENCE();                     // prior S reads retired before overwrite
    lds_c_write(Sw, stg, l15, l4);
    LGKM_FENCE();
    lds_read_afrags(Sw, l15, l4, ahi, alo);
    zero8(acc);
    gemm3(ahi, alo, frags + 7 * FRAG_W, lane, acc);
    store_c(outf, acc, sbo, row0, l15, l4);
}

// ---------------------------------------------------------------------------
extern "C" void kernel_launch(void* const* d_in, const int* in_sizes, int n_in,
                              void* d_out, int out_size, void* d_ws, size_t ws_size,
                              hipStream_t stream)
{
    const int*   uids       = (const int*)d_in[0];
    const int*   um         = (const int*)d_in[2];
    const float* user_table = (const float*)d_in[3];
    const float* item_table = (const float*)d_in[5];
    const float* gwq = (const float*)d_in[6];  const float* gbq = (const float*)d_in[7];
    const float* gwk = (const float*)d_in[8];  const float* gbk = (const float*)d_in[9];
    const float* gwv = (const float*)d_in[10]; const float* gbv = (const float*)d_in[11];
    const float* gwo = (const float*)d_in[12]; const float* gbo = (const float*)d_in[13];
    const float* swq = (const float*)d_in[14]; const float* sbq = (const float*)d_in[15];
    const float* swk = (const float*)d_in[16]; const float* sbk = (const float*)d_in[17];
    const float* swv = (const float*)d_in[18]; const float* sbv = (const float*)d_in[19];
    const float* swo = (const float*)d_in[20]; const float* sbo = (const float*)d_in[21];

    char* ws = (char*)d_ws;
    u16*   kt    = (u16*)ws;   ws += (size_t)NI_SZ * 128 * 2;     // 25.6 MB
    u16*   vt    = (u16*)ws;   ws += (size_t)NI_SZ * 128 * 2;     // 25.6 MB
    u16*   frags = (u16*)ws;   ws += (size_t)8 * FRAG_W * 2;      // 0.5 MB
    float* qg  = (float*)ws;   ws += (size_t)B_SZ * 128 * 4;
    float* qs  = (float*)ws;   ws += (size_t)B_SZ * 128 * 4;
    float* v1  = (float*)ws;   ws += (size_t)B_SZ * 128 * 4;
    float* yb  = (float*)ws;   ws += (size_t)B_SZ * 128 * 4;
    float* d1g = (float*)ws;   ws += (size_t)B_SZ * 4;
    float* outf = (float*)d_out;

    // W order: 0 gwq, 1 gwk, 2 gwv, 3 gwo, 4 swq, 5 swk, 6 swv, 7 swo
    WPtrs wp; wp.p[0]=gwq; wp.p[1]=gwk; wp.p[2]=gwv; wp.p[3]=gwo;
              wp.p[4]=swq; wp.p[5]=swk; wp.p[6]=swv; wp.p[7]=swo;
    prep_frags<<<512, 256, 0, stream>>>(wp, frags);

    // Item K+V: 12500 wave-units
    item_kv<<<3125, 256, 0, stream>>>(item_table, frags, gbk, gbv, kt, vt);

    // Node projections + d1: 1024 wave-units
    node4_fused<<<256, 256, 0, stream>>>(user_table, uids, frags,
                                         gbq, sbq, sbk, sbv, qg, qs, v1, d1g);

    gat_attn<<<B_SZ / 4, 256, 0, stream>>>(qg, kt, vt, um, yb);

    // Full semantic stage: 1024 wave-units
    sem_fused<<<256, 256, 0, stream>>>(yb, qs, v1, d1g, frags,
                                       gbo, sbk, sbv, sbo, outf);
}

// Round 6
// 276.482 us; speedup vs baseline: 1.1815x; 1.1815x over previous
//
#include <hip/hip_runtime.h>
#include <math.h>

typedef __bf16 bf16_t;
typedef bf16_t bf16x8 __attribute__((ext_vector_type(8)));
typedef float  f32x4  __attribute__((ext_vector_type(4)));
typedef unsigned short u16;

#define B_SZ   16384
#define H_SZ   50
#define NI_SZ  100000
#define SCALE  0.08838834764831845f   /* 1/sqrt(128) */
#define FRAG_W 32768                  /* u16 elems per W (hi 16384 + lo 16384) */

// Logical-k bijection used consistently for A and B frags of
// mfma_f32_16x16x32_bf16:  k = kk*32 + 16*(e>>2) + 4*l4 + (e&3).
// C/D layout (HW): col = lane&15, row = (lane>>4)*4 + reg.

// ---------------------------------------------------------------------------
// Prep: W[k][n] (f32 128x128) -> frag-ready hi/lo bf16; a wave's (kk,nblk)
// B-frag read is 1024 contiguous bytes at ((kk*8+nblk)*64+lane)*8.
// ---------------------------------------------------------------------------
struct WPtrs { const float* p[8]; };

__global__ void prep_frags(WPtrs wp, u16* __restrict__ dst)
{
    int tid = blockIdx.x * 256 + threadIdx.x;      // 8 * 16384 threads
    int w = tid >> 14, idx = tid & 16383;
    int k = idx >> 7, n = idx & 127;
    float v = wp.p[w][idx];
    bf16_t hi = (bf16_t)v;
    bf16_t lo = (bf16_t)(v - (float)hi);
    int kk = k >> 5, k32 = k & 31;
    int e  = ((k32 >> 4) & 1) * 4 + (k32 & 3);
    int l4 = (k32 >> 2) & 3;
    int lane = l4 * 16 + (n & 15);
    int pos = ((kk * 8 + (n >> 4)) * 64 + lane) * 8 + e;
    union { bf16_t b; u16 u; } ch, cl; ch.b = hi; cl.b = lo;
    dst[(size_t)w * FRAG_W + pos]         = ch.u;
    dst[(size_t)w * FRAG_W + 16384 + pos] = cl.u;
}

// ---------------------------------------------------------------------------
// Shared device helpers
// ---------------------------------------------------------------------------
__device__ __forceinline__ void repack8(f32x4 a0, f32x4 a1, bf16x8& hi, bf16x8& lo)
{
#pragma unroll
    for (int e = 0; e < 4; ++e) {
        bf16_t h0 = (bf16_t)a0[e]; hi[e] = h0; lo[e] = (bf16_t)(a0[e] - (float)h0);
        bf16_t h1 = (bf16_t)a1[e]; hi[4 + e] = h1; lo[4 + e] = (bf16_t)(a1[e] - (float)h1);
    }
}

// Partial GEMM over NB n-blocks starting at n0: 16x128 @ 128x(NB*16),
// 3-term split-bf16 (~fp32)
template<int NB>
__device__ __forceinline__ void gemm3_nb(const bf16x8 ahi[4], const bf16x8 alo[4],
                                         const u16* __restrict__ fh, int lane, int n0,
                                         f32x4 acc[NB])
{
#pragma unroll
    for (int kk = 0; kk < 4; ++kk)
#pragma unroll
        for (int ni = 0; ni < NB; ++ni) {
            int foff = ((kk * 8 + (n0 + ni)) * 64 + lane) * 8;
            bf16x8 bhi = *(const bf16x8*)(fh + foff);
            bf16x8 blo = *(const bf16x8*)(fh + 16384 + foff);
            acc[ni] = __builtin_amdgcn_mfma_f32_16x16x32_bf16(ahi[kk], bhi, acc[ni], 0, 0, 0);
            acc[ni] = __builtin_amdgcn_mfma_f32_16x16x32_bf16(alo[kk], bhi, acc[ni], 0, 0, 0);
            acc[ni] = __builtin_amdgcn_mfma_f32_16x16x32_bf16(ahi[kk], blo, acc[ni], 0, 0, 0);
        }
}

// Load a contiguous/gathered 16x128 f32 tile as A-frags (lane l15 = row)
__device__ __forceinline__ void load_afrags(const float* __restrict__ Ar, int l4,
                                            bf16x8 ahi[4], bf16x8 alo[4])
{
#pragma unroll
    for (int kk = 0; kk < 4; ++kk) {
        f32x4 a0 = *(const f32x4*)(Ar + kk * 32 + 4 * l4);
        f32x4 a1 = *(const f32x4*)(Ar + kk * 32 + 16 + 4 * l4);
        repack8(a0, a1, ahi[kk], alo[kk]);
    }
}

// Read full 16x128 f32 tile from LDS (row stride 132) as A-frags
__device__ __forceinline__ void lds_read_afrags(const float* __restrict__ S, int l15, int l4,
                                                bf16x8 ahi[4], bf16x8 alo[4])
{
#pragma unroll
    for (int kk = 0; kk < 4; ++kk) {
        f32x4 a0 = *(const f32x4*)(S + l15 * 132 + kk * 32 + 4 * l4);
        f32x4 a1 = *(const f32x4*)(S + l15 * 132 + kk * 32 + 16 + 4 * l4);
        repack8(a0, a1, ahi[kk], alo[kk]);
    }
}

#define LGKM_FENCE() do { \
    __asm__ volatile("s_waitcnt lgkmcnt(0)" ::: "memory"); \
    __builtin_amdgcn_sched_barrier(0); } while (0)

// ---------------------------------------------------------------------------
// Item K+V GEMM: block handles one weight (K or V); hi B-frags staged in LDS
// (32KB) once, 4 waves grid-stride tiles reading B from LDS.  bf16 out via
// LDS bounce -> 1KB-contiguous wave stores.
// ---------------------------------------------------------------------------
__global__ __launch_bounds__(256, 4)
void item_kv(const float* __restrict__ A, const u16* __restrict__ frags,
             const float* __restrict__ bk, const float* __restrict__ bv,
             u16* __restrict__ kt, u16* __restrict__ vt)
{
    __shared__ u16 Bh[16384];            // 32 KB: hi frags of this block's W
    __shared__ u16 bounce[4 * 16 * 136]; // 17 KB
    const int t = threadIdx.x, wave = t >> 6, lane = t & 63;
    const int l15 = lane & 15, l4 = lane >> 4;
    const int w = blockIdx.x & 1;                     // 0 -> K, 1 -> V
    const int blkw = blockIdx.x >> 1;                 // 0..511 per w
    const float* bias = w ? bv : bk;
    u16* out = w ? vt : kt;
    const u16* fh = frags + (size_t)(w ? 2 : 1) * FRAG_W;

    // stage hi frags: 256 threads x 64 u16 (8 x 16B)
#pragma unroll
    for (int j = 0; j < 8; ++j)
        *(ulonglong2*)(Bh + t * 64 + j * 8) = *(const ulonglong2*)(fh + t * 64 + j * 8);
    __syncthreads();

    float bvn[8];
#pragma unroll
    for (int n = 0; n < 8; ++n) bvn[n] = bias[n * 16 + l15];

    const int NT = NI_SZ >> 4;                        // 6250 tiles
    for (int tb = blkw * 4; tb < NT; tb += 512 * 4) {
        const int tile = tb + wave;
        if (tile >= NT) break;
        const int row0 = tile * 16;

        const float* Ar = A + (size_t)(row0 + l15) * 128;
        bf16x8 ahi[4];
#pragma unroll
        for (int kk = 0; kk < 4; ++kk) {
            f32x4 a0 = *(const f32x4*)(Ar + kk * 32 + 4 * l4);
            f32x4 a1 = *(const f32x4*)(Ar + kk * 32 + 16 + 4 * l4);
#pragma unroll
            for (int e = 0; e < 4; ++e) {
                ahi[kk][e]     = (bf16_t)a0[e];
                ahi[kk][4 + e] = (bf16_t)a1[e];
            }
        }

        f32x4 acc[8];
#pragma unroll
        for (int n = 0; n < 8; ++n) acc[n] = (f32x4){0.f, 0.f, 0.f, 0.f};
#pragma unroll
        for (int kk = 0; kk < 4; ++kk)
#pragma unroll
            for (int n = 0; n < 8; ++n) {
                bf16x8 bhi = *(const bf16x8*)(Bh + ((kk * 8 + n) * 64 + lane) * 8);
                acc[n] = __builtin_amdgcn_mfma_f32_16x16x32_bf16(ahi[kk], bhi, acc[n], 0, 0, 0);
            }

        u16* bb = bounce + wave * (16 * 136);
#pragma unroll
        for (int n = 0; n < 8; ++n)
#pragma unroll
            for (int r = 0; r < 4; ++r) {
                float v = acc[n][r] + bvn[n];
                v = v > 0.f ? v : 0.f;
                union { bf16_t b; u16 u; } c; c.b = (bf16_t)v;
                bb[(l4 * 4 + r) * 136 + n * 16 + l15] = c.u;
            }
        LGKM_FENCE();
#pragma unroll
        for (int j = 0; j < 4; ++j) {
            int row = j * 4 + l4;
            const u16* sp = bb + row * 136 + l15 * 8;
            u16* ob = out + (size_t)(row0 + row) * 128 + l15 * 8;
            *(ulonglong2*)ob = *(const ulonglong2*)sp;
        }
        LGKM_FENCE();   // bounce reuse safety across iterations
    }
}

// ---------------------------------------------------------------------------
// Fused node projections, block-per-tile, column-split across 4 waves
// (wave w owns n-blocks {2w, 2w+1}):
//   qg = relu(node@gwq+gbq), qs = relu(node@swq+sbq),
//   k1 = relu(node@swk+sbk) (regs only), v1 = relu(node@swv+sbv),
//   d1[b] = qs[b] . k1[b]  (LDS cross-wave reduce).
// ---------------------------------------------------------------------------
__global__ __launch_bounds__(256, 4)
void node4_fused(const float* __restrict__ ut, const int* __restrict__ uids,
                 const u16* __restrict__ frags,
                 const float* __restrict__ gbq, const float* __restrict__ sbq,
                 const float* __restrict__ sbk, const float* __restrict__ sbv,
                 float* __restrict__ qg, float* __restrict__ qs,
                 float* __restrict__ v1, float* __restrict__ d1g)
{
    __shared__ float dpart[4][16];
    const int t = threadIdx.x, wave = t >> 6, lane = t & 63;
    const int l15 = lane & 15, l4 = lane >> 4;
    const int n0 = wave * 2;
    const int row0 = blockIdx.x * 16;

    const float* Ar = ut + (size_t)uids[row0 + l15] * 128;
    bf16x8 ahi[4], alo[4];
    load_afrags(Ar, l4, ahi, alo);

    f32x4 acc[2];

    // qg
    acc[0] = (f32x4){0,0,0,0}; acc[1] = (f32x4){0,0,0,0};
    gemm3_nb<2>(ahi, alo, frags + 0 * FRAG_W, lane, n0, acc);
#pragma unroll
    for (int ni = 0; ni < 2; ++ni) {
        float bv = gbq[(n0 + ni) * 16 + l15];
#pragma unroll
        for (int r = 0; r < 4; ++r) {
            float v = acc[ni][r] + bv;
            qg[(size_t)(row0 + l4 * 4 + r) * 128 + (n0 + ni) * 16 + l15] = v > 0.f ? v : 0.f;
        }
    }

    // qs (keep cols in regs for d1)
    float qsr[2][4];
    acc[0] = (f32x4){0,0,0,0}; acc[1] = (f32x4){0,0,0,0};
    gemm3_nb<2>(ahi, alo, frags + 4 * FRAG_W, lane, n0, acc);
#pragma unroll
    for (int ni = 0; ni < 2; ++ni) {
        float bv = sbq[(n0 + ni) * 16 + l15];
#pragma unroll
        for (int r = 0; r < 4; ++r) {
            float v = acc[ni][r] + bv;
            qsr[ni][r] = v > 0.f ? v : 0.f;
            qs[(size_t)(row0 + l4 * 4 + r) * 128 + (n0 + ni) * 16 + l15] = qsr[ni][r];
        }
    }

    // k1 (regs only) + d1 partial
    acc[0] = (f32x4){0,0,0,0}; acc[1] = (f32x4){0,0,0,0};
    gemm3_nb<2>(ahi, alo, frags + 5 * FRAG_W, lane, n0, acc);
    float d1[4] = {0.f, 0.f, 0.f, 0.f};
#pragma unroll
    for (int ni = 0; ni < 2; ++ni) {
        float bv = sbk[(n0 + ni) * 16 + l15];
#pragma unroll
        for (int r = 0; r < 4; ++r) {
            float v = acc[ni][r] + bv;
            v = v > 0.f ? v : 0.f;
            d1[r] += qsr[ni][r] * v;
        }
    }
#pragma unroll
    for (int r = 0; r < 4; ++r) {
#pragma unroll
        for (int off = 8; off; off >>= 1) d1[r] += __shfl_xor(d1[r], off);
    }
    if (l15 == 0) {
#pragma unroll
        for (int r = 0; r < 4; ++r) dpart[wave][l4 * 4 + r] = d1[r];
    }

    // v1
    acc[0] = (f32x4){0,0,0,0}; acc[1] = (f32x4){0,0,0,0};
    gemm3_nb<2>(ahi, alo, frags + 6 * FRAG_W, lane, n0, acc);
#pragma unroll
    for (int ni = 0; ni < 2; ++ni) {
        float bv = sbv[(n0 + ni) * 16 + l15];
#pragma unroll
        for (int r = 0; r < 4; ++r) {
            float v = acc[ni][r] + bv;
            v1[(size_t)(row0 + l4 * 4 + r) * 128 + (n0 + ni) * 16 + l15] = v > 0.f ? v : 0.f;
        }
    }

    __syncthreads();
    if (t < 16)
        d1g[row0 + t] = dpart[0][t] + dpart[1][t] + dpart[2][t] + dpart[3][t];
}

// ---------------------------------------------------------------------------
// GAT attention: wave per batch row, V preloaded to regs.
// ---------------------------------------------------------------------------
__global__ __launch_bounds__(256)
void gat_attn(const float* __restrict__ qg, const u16* __restrict__ kt,
              const u16* __restrict__ vt, const int* __restrict__ um,
              float* __restrict__ y)
{
    __shared__ float qsh[4][128];
    const int wave = threadIdx.x >> 6, lane = threadIdx.x & 63;
    const int b = blockIdx.x * 4 + wave;

    float2 q2 = *(const float2*)(qg + (size_t)b * 128 + lane * 2);
    qsh[wave][lane * 2]     = q2.x;
    qsh[wave][lane * 2 + 1] = q2.y;

    int mrow = (lane < H_SZ) ? um[((size_t)b * H_SZ + lane) * 2] : 0;

    unsigned vreg[H_SZ];
#pragma unroll
    for (int h = 0; h < H_SZ; ++h) {
        int vr = __shfl(mrow, h);
        vreg[h] = *(const unsigned*)(vt + (size_t)vr * 128 + lane * 2);
    }
    __syncthreads();

    float s = -1e30f;
    if (lane < H_SZ) {
        const u16* kr = kt + (size_t)mrow * 128;
        float acc = 0.f;
#pragma unroll
        for (int c = 0; c < 4; ++c) {
            bf16x8 kc[4];
#pragma unroll
            for (int j = 0; j < 4; ++j) kc[j] = *(const bf16x8*)(kr + (c * 4 + j) * 8);
#pragma unroll
            for (int j = 0; j < 4; ++j)
#pragma unroll
                for (int e = 0; e < 8; ++e)
                    acc += (float)kc[j][e] * qsh[wave][(c * 4 + j) * 8 + e];
        }
        s = acc * SCALE;
    }
    float m = s;
#pragma unroll
    for (int off = 32; off; off >>= 1) m = fmaxf(m, __shfl_xor(m, off));
    float p = (lane < H_SZ) ? __expf(s - m) : 0.f;
    float sum = p;
#pragma unroll
    for (int off = 32; off; off >>= 1) sum += __shfl_xor(sum, off);
    p /= sum;

    float ax = 0.f, ay = 0.f;
#pragma unroll
    for (int h = 0; h < H_SZ; ++h) {
        float ph = __shfl(p, h);
        unsigned u = vreg[h];
        ax += ph * __uint_as_float(u << 16);
        ay += ph * __uint_as_float(u & 0xffff0000u);
    }
    *(float2*)(y + (size_t)b * 128 + lane * 2) = (float2){ax, ay};
}

// ---------------------------------------------------------------------------
// Fused semantic stage, block-per-tile, column-split across 4 waves:
//   agg = relu(yb@gwo+gbo)  (block LDS tile exchange)
//   k2/v2 cols in regs; d2 = qs.k2 (LDS reduce); softmax(d1,d2);
//   ys = p1*v1 + p2*v2  (LDS tile exchange);  out = relu(ys@swo+sbo).
// ---------------------------------------------------------------------------
__global__ __launch_bounds__(256, 4)
void sem_fused(const float* __restrict__ yb, const float* __restrict__ qs,
               const float* __restrict__ v1, const float* __restrict__ d1g,
               const u16* __restrict__ frags,
               const float* __restrict__ gbo, const float* __restrict__ sbk,
               const float* __restrict__ sbv, const float* __restrict__ sbo,
               float* __restrict__ outf)
{
    __shared__ float S[16 * 132];
    __shared__ float dpart[4][16];
    const int t = threadIdx.x, wave = t >> 6, lane = t & 63;
    const int l15 = lane & 15, l4 = lane >> 4;
    const int n0 = wave * 2;
    const int row0 = blockIdx.x * 16;

    // ---- stage 1: agg cols -> LDS
    bf16x8 ahi[4], alo[4];
    load_afrags(yb + (size_t)(row0 + l15) * 128, l4, ahi, alo);
    f32x4 acc[2];
    acc[0] = (f32x4){0,0,0,0}; acc[1] = (f32x4){0,0,0,0};
    gemm3_nb<2>(ahi, alo, frags + 3 * FRAG_W, lane, n0, acc);
#pragma unroll
    for (int ni = 0; ni < 2; ++ni) {
        float bv = gbo[(n0 + ni) * 16 + l15];
#pragma unroll
        for (int r = 0; r < 4; ++r) {
            float v = acc[ni][r] + bv;
            S[(l4 * 4 + r) * 132 + (n0 + ni) * 16 + l15] = v > 0.f ? v : 0.f;
        }
    }
    __syncthreads();
    lds_read_afrags(S, l15, l4, ahi, alo);        // agg as A-frags

    // ---- stage 2: k2, v2 cols
    float k2c[2][4], v2c[2][4];
    acc[0] = (f32x4){0,0,0,0}; acc[1] = (f32x4){0,0,0,0};
    gemm3_nb<2>(ahi, alo, frags + 5 * FRAG_W, lane, n0, acc);
#pragma unroll
    for (int ni = 0; ni < 2; ++ni) {
        float bv = sbk[(n0 + ni) * 16 + l15];
#pragma unroll
        for (int r = 0; r < 4; ++r) {
            float v = acc[ni][r] + bv;
            k2c[ni][r] = v > 0.f ? v : 0.f;
        }
    }
    acc[0] = (f32x4){0,0,0,0}; acc[1] = (f32x4){0,0,0,0};
    gemm3_nb<2>(ahi, alo, frags + 6 * FRAG_W, lane, n0, acc);
#pragma unroll
    for (int ni = 0; ni < 2; ++ni) {
        float bv = sbv[(n0 + ni) * 16 + l15];
#pragma unroll
        for (int r = 0; r < 4; ++r) {
            float v = acc[ni][r] + bv;
            v2c[ni][r] = v > 0.f ? v : 0.f;
        }
    }

    // ---- d2 partial (needs only this wave's qs cols)
    float d2[4] = {0.f, 0.f, 0.f, 0.f};
    float qsv[2][4];
#pragma unroll
    for (int ni = 0; ni < 2; ++ni)
#pragma unroll
        for (int r = 0; r < 4; ++r) {
            qsv[ni][r] = qs[(size_t)(row0 + l4 * 4 + r) * 128 + (n0 + ni) * 16 + l15];
            d2[r] += qsv[ni][r] * k2c[ni][r];
        }
    (void)qsv;
#pragma unroll
    for (int r = 0; r < 4; ++r) {
#pragma unroll
        for (int off = 8; off; off >>= 1) d2[r] += __shfl_xor(d2[r], off);
    }
    if (l15 == 0) {
#pragma unroll
        for (int r = 0; r < 4; ++r) dpart[wave][l4 * 4 + r] = d2[r];
    }
    __syncthreads();   // dpart complete; also all S reads of stage 1 retired

    // ---- softmax + ys cols -> LDS
    float p1[4], p2[4];
#pragma unroll
    for (int r = 0; r < 4; ++r) {
        int ridx = l4 * 4 + r;
        float d2t = dpart[0][ridx] + dpart[1][ridx] + dpart[2][ridx] + dpart[3][ridx];
        float s1 = d1g[row0 + ridx] * SCALE;
        float s2 = d2t * SCALE;
        float m = fmaxf(s1, s2);
        float e1 = __expf(s1 - m), e2 = __expf(s2 - m);
        float inv = 1.f / (e1 + e2);
        p1[r] = e1 * inv; p2[r] = e2 * inv;
    }
#pragma unroll
    for (int ni = 0; ni < 2; ++ni)
#pragma unroll
        for (int r = 0; r < 4; ++r) {
            float vv1 = v1[(size_t)(row0 + l4 * 4 + r) * 128 + (n0 + ni) * 16 + l15];
            S[(l4 * 4 + r) * 132 + (n0 + ni) * 16 + l15] = p1[r] * vv1 + p2[r] * v2c[ni][r];
        }
    __syncthreads();
    lds_read_afrags(S, l15, l4, ahi, alo);        // ys as A-frags

    // ---- stage 3: out cols
    acc[0] = (f32x4){0,0,0,0}; acc[1] = (f32x4){0,0,0,0};
    gemm3_nb<2>(ahi, alo, frags + 7 * FRAG_W, lane, n0, acc);
#pragma unroll
    for (int ni = 0; ni < 2; ++ni) {
        float bv = sbo[(n0 + ni) * 16 + l15];
#pragma unroll
        for (int r = 0; r < 4; ++r) {
            float v = acc[ni][r] + bv;
            outf[(size_t)(row0 + l4 * 4 + r) * 128 + (n0 + ni) * 16 + l15] = v > 0.f ? v : 0.f;
        }
    }
}

// ---------------------------------------------------------------------------
extern "C" void kernel_launch(void* const* d_in, const int* in_sizes, int n_in,
                              void* d_out, int out_size, void* d_ws, size_t ws_size,
                              hipStream_t stream)
{
    const int*   uids       = (const int*)d_in[0];
    const int*   um         = (const int*)d_in[2];
    const float* user_table = (const float*)d_in[3];
    const float* item_table = (const float*)d_in[5];
    const float* gwq = (const float*)d_in[6];  const float* gbq = (const float*)d_in[7];
    const float* gwk = (const float*)d_in[8];  const float* gbk = (const float*)d_in[9];
    const float* gwv = (const float*)d_in[10]; const float* gbv = (const float*)d_in[11];
    const float* gwo = (const float*)d_in[12]; const float* gbo = (const float*)d_in[13];
    const float* swq = (const float*)d_in[14]; const float* sbq = (const float*)d_in[15];
    const float* swk = (const float*)d_in[16]; const float* sbk = (const float*)d_in[17];
    const float* swv = (const float*)d_in[18]; const float* sbv = (const float*)d_in[19];
    const float* swo = (const float*)d_in[20]; const float* sbo = (const float*)d_in[21];

    char* ws = (char*)d_ws;
    u16*   kt    = (u16*)ws;   ws += (size_t)NI_SZ * 128 * 2;     // 25.6 MB
    u16*   vt    = (u16*)ws;   ws += (size_t)NI_SZ * 128 * 2;     // 25.6 MB
    u16*   frags = (u16*)ws;   ws += (size_t)8 * FRAG_W * 2;      // 0.5 MB
    float* qg  = (float*)ws;   ws += (size_t)B_SZ * 128 * 4;
    float* qs  = (float*)ws;   ws += (size_t)B_SZ * 128 * 4;
    float* v1  = (float*)ws;   ws += (size_t)B_SZ * 128 * 4;
    float* yb  = (float*)ws;   ws += (size_t)B_SZ * 128 * 4;
    float* d1g = (float*)ws;   ws += (size_t)B_SZ * 4;
    float* outf = (float*)d_out;

    // W order: 0 gwq, 1 gwk, 2 gwv, 3 gwo, 4 swq, 5 swk, 6 swv, 7 swo
    WPtrs wp; wp.p[0]=gwq; wp.p[1]=gwk; wp.p[2]=gwv; wp.p[3]=gwo;
              wp.p[4]=swq; wp.p[5]=swk; wp.p[6]=swv; wp.p[7]=swo;
    prep_frags<<<512, 256, 0, stream>>>(wp, frags);

    // Item K+V: 1024 blocks (512 per weight), B hi-frags LDS-resident
    item_kv<<<1024, 256, 0, stream>>>(item_table, frags, gbk, gbv, kt, vt);

    // Node projections + d1: block per 16-row tile, column-split waves
    node4_fused<<<1024, 256, 0, stream>>>(user_table, uids, frags,
                                          gbq, sbq, sbk, sbv, qg, qs, v1, d1g);

    gat_attn<<<B_SZ / 4, 256, 0, stream>>>(qg, kt, vt, um, yb);

    // Full semantic stage: block per 16-row tile, column-split waves
    sem_fused<<<1024, 256, 0, stream>>>(yb, qs, v1, d1g, frags,
                                        gbo, sbk, sbv, sbo, outf);
}